// Round 9
// baseline (3526.190 us; speedup 1.0000x reference)
//
#include <hip/hip_runtime.h>
#include <hip/hip_bf16.h>

// B=64, S=2048, WIN=50, E=128, H=256, G=4H=1024.
#define B_ 64
#define S_ 2048
#define W_ 50
#define E_ 128
#define H_ 256
#define G_ 1024

typedef unsigned short u16;
typedef unsigned int u32;

// Module-global scratch (BSS; d_ws untrusted).
__device__ int g_mode;                          // 0 = bf16 buffers, 1 = fp32 buffers
__device__ u16 g_WihT[E_ * G_];                 // [e][4u+q] = Wih[q*H+u][e]  (bf16)
__device__ u32 g_Wi8[G_ * 64];                  // [c][j]: 4×i8 = Whh[row(c)][4j..4j+3], row(c)=(c&3)*256+(c>>2)
__device__ float g_wscale[G_];                  // per-column dequant: max|W[:,c]| /(127*127)
__device__ u16 g_xg[(size_t)B_ * S_ * G_];      // [b][s][1024] bf16, biases folded (validated)

__device__ __forceinline__ float b2f(u16 u) {
    union { u32 i; float f; } v;
    v.i = ((u32)u) << 16;
    return v.f;
}
__device__ __forceinline__ u16 f2b(float f) {
    __hip_bfloat16 h = __float2bfloat16(f);
    return *reinterpret_cast<u16*>(&h);
}
__device__ __forceinline__ float ldin(int mode, const void* p, size_t i) {
    return mode ? ((const float*)p)[i] : b2f(((const u16*)p)[i]);
}
__device__ __forceinline__ float clamp30(float x) {
    return fminf(fmaxf(x, -30.0f), 30.0f);
}
__device__ __forceinline__ float sigmoidf_(float x) { return 1.0f / (1.0f + __expf(-x)); }
__device__ __forceinline__ float tanhf_(float x) {
    float e = __expf(2.0f * x);
    return 1.0f - 2.0f / (e + 1.0f);
}
// int8x4 dot: acc += sum_i (i8)a[i] * (i8)b[i]
__device__ __forceinline__ int dot4i8(u32 a, u32 b, int acc) {
#if __has_builtin(__builtin_amdgcn_sdot4)
    return __builtin_amdgcn_sdot4(a, b, acc, false);
#else
    acc += (int)(signed char)(a)       * (int)(signed char)(b);
    acc += (int)(signed char)(a >> 8)  * (int)(signed char)(b >> 8);
    acc += (int)(signed char)(a >> 16) * (int)(signed char)(b >> 16);
    acc += (int)(signed char)(a >> 24) * (int)(signed char)(b >> 24);
    return acc;
#endif
}

// ---------- K0: dtype sniffer (validated) ----------
__global__ void sniff_kernel(const u16* __restrict__ wemb) {
    int sane = 0;
    for (int i = 0; i < 2048; ++i) {
        int ex = (wemb[i] >> 7) & 0xFF;
        if (ex == 0 || (ex >= 96 && ex <= 143)) ++sane;
    }
    g_mode = (sane >= 1900) ? 0 : 1;
}

// ---------- K0b: Wih gate-interleaved transpose (for xg_kernel) ----------
__global__ __launch_bounds__(256) void transpose_wih(const void* __restrict__ src) {
    const int mode = g_mode;
    int i = blockIdx.x * 256 + threadIdx.x;          // i = e*G + 4u+q
    int e = i >> 10, r = i & 1023, u = r >> 2, q = r & 3;
    g_WihT[i] = f2b(ldin(mode, src, (size_t)((q << 15) + (u << 7) + e)));
}

// ---------- K0c: Whh -> int8 per-column-scaled, [c][j] layout (validated) ----------
__global__ __launch_bounds__(256) void prep_wi8(const void* __restrict__ src) {
    const int mode = g_mode;
    int c = blockIdx.x * 256 + threadIdx.x;          // 0..1023
    int row = ((c & 3) << 8) + (c >> 2);
    const size_t base = (size_t)row * H_;
    float m = 0.0f;
    for (int k = 0; k < H_; ++k) m = fmaxf(m, fabsf(ldin(mode, src, base + k)));
    float inv = (m > 0.0f) ? 127.0f / m : 0.0f;
    g_wscale[c] = m / (127.0f * 127.0f);             // w-scale * h-scale(1/127)
    for (int j = 0; j < 64; ++j) {
        u32 pk = 0;
#pragma unroll
        for (int i = 0; i < 4; ++i) {
            int q = (int)rintf(ldin(mode, src, base + 4 * j + i) * inv);
            q = max(-127, min(127, q));
            pk |= ((u32)(q & 0xff)) << (8 * i);
        }
        g_Wi8[(size_t)c * 64 + j] = pk;              // contiguous per column
    }
}

// ---------- K1: fused embedding + input projection (validated round 4) ----------
__global__ __launch_bounds__(256) void xg_kernel(const void* __restrict__ pw,
                                                 const void* __restrict__ Wemb,
                                                 const void* __restrict__ bemb,
                                                 const void* __restrict__ bih,
                                                 const void* __restrict__ bhh) {
    const int mode = g_mode;
    const int t = threadIdx.x;
    const int m0 = blockIdx.x * 16;
    __shared__ float pw16[16][W_ + 2];
    __shared__ float Wl[E_ * 51];
    __shared__ __align__(16) float erow[16][E_];

    for (int i = t; i < E_ * W_; i += 256) {
        int e = i / W_, w = i - e * W_;
        Wl[e * 51 + w] = ldin(mode, Wemb, i);
    }
    for (int i = t; i < 16 * W_; i += 256) {
        int r = i / W_, w = i - r * W_;
        pw16[r][w] = ldin(mode, pw, (size_t)(m0 + r) * W_ + w);
    }
    __syncthreads();

#pragma unroll
    for (int i = 0; i < 8; ++i) {
        int idx = i * 256 + t;
        int r = idx >> 7, e = idx & 127;
        float a = ldin(mode, bemb, e);
        const float* wr = &Wl[e * 51];
#pragma unroll
        for (int w = 0; w < W_; ++w) a = fmaf(pw16[r][w], wr[w], a);
        erow[r][e] = fmaxf(a, 0.0f);
    }
    __syncthreads();

    const int g0 = 4 * t;
    float acc[16][4];
    {
        float b0 = ldin(mode, bih, t) + ldin(mode, bhh, t);
        float b1 = ldin(mode, bih, H_ + t) + ldin(mode, bhh, H_ + t);
        float b2 = ldin(mode, bih, 2 * H_ + t) + ldin(mode, bhh, 2 * H_ + t);
        float b3 = ldin(mode, bih, 3 * H_ + t) + ldin(mode, bhh, 3 * H_ + t);
#pragma unroll
        for (int r = 0; r < 16; ++r) { acc[r][0] = b0; acc[r][1] = b1; acc[r][2] = b2; acc[r][3] = b3; }
    }
    for (int e = 0; e < E_; e += 4) {
        ushort4 w0 = *(const ushort4*)(g_WihT + (size_t)(e + 0) * G_ + g0);
        ushort4 w1 = *(const ushort4*)(g_WihT + (size_t)(e + 1) * G_ + g0);
        ushort4 w2 = *(const ushort4*)(g_WihT + (size_t)(e + 2) * G_ + g0);
        ushort4 w3 = *(const ushort4*)(g_WihT + (size_t)(e + 3) * G_ + g0);
        float f00 = b2f(w0.x), f01 = b2f(w0.y), f02 = b2f(w0.z), f03 = b2f(w0.w);
        float f10 = b2f(w1.x), f11 = b2f(w1.y), f12 = b2f(w1.z), f13 = b2f(w1.w);
        float f20 = b2f(w2.x), f21 = b2f(w2.y), f22 = b2f(w2.z), f23 = b2f(w2.w);
        float f30 = b2f(w3.x), f31 = b2f(w3.y), f32 = b2f(w3.z), f33 = b2f(w3.w);
#pragma unroll
        for (int r = 0; r < 16; ++r) {
            float4 ev = *(const float4*)&erow[r][e];
            acc[r][0] = fmaf(ev.x, f00, acc[r][0]); acc[r][1] = fmaf(ev.x, f01, acc[r][1]);
            acc[r][2] = fmaf(ev.x, f02, acc[r][2]); acc[r][3] = fmaf(ev.x, f03, acc[r][3]);
            acc[r][0] = fmaf(ev.y, f10, acc[r][0]); acc[r][1] = fmaf(ev.y, f11, acc[r][1]);
            acc[r][2] = fmaf(ev.y, f12, acc[r][2]); acc[r][3] = fmaf(ev.y, f13, acc[r][3]);
            acc[r][0] = fmaf(ev.z, f20, acc[r][0]); acc[r][1] = fmaf(ev.z, f21, acc[r][1]);
            acc[r][2] = fmaf(ev.z, f22, acc[r][2]); acc[r][3] = fmaf(ev.z, f23, acc[r][3]);
            acc[r][0] = fmaf(ev.w, f30, acc[r][0]); acc[r][1] = fmaf(ev.w, f31, acc[r][1]);
            acc[r][2] = fmaf(ev.w, f32, acc[r][2]); acc[r][3] = fmaf(ev.w, f33, acc[r][3]);
        }
    }
#pragma unroll
    for (int r = 0; r < 16; ++r) {
        ushort4 sv;
        sv.x = f2b(acc[r][0]); sv.y = f2b(acc[r][1]);
        sv.z = f2b(acc[r][2]); sv.w = f2b(acc[r][3]);
        *(ushort4*)(g_xg + (size_t)(m0 + r) * G_ + g0) = sv;
    }
}

// ---------- K2: recurrence; W_hh pinned in VGPRs via inline-asm loads ----------
// 64 blocks x 1024 threads; thread t owns gate-column t (4*unit+gate), all K=256 as
// 16 uint4 loaded by asm volatile (cannot be rematerialized -> stays in registers).
// h exchanged as packed i8 (scale 1/127) through 256 B of LDS.
__global__ __launch_bounds__(1024, 4) void lstm_i8(const void* __restrict__ Wout,
                                                   const void* __restrict__ bout,
                                                   const void* __restrict__ h0,
                                                   const void* __restrict__ c0,
                                                   void* __restrict__ yv) {
    const int mode = g_mode;
    const int t = threadIdx.x;
    const int b = blockIdx.x;

    __shared__ __align__(16) u32 h8[H_ / 4];     // h as i8, 64 words
    __shared__ __align__(16) float gl[G_];       // gate ACTIVATIONS (post-sigmoid/tanh)
    __shared__ float red[4];

    // --- weights into 16 uint4 via inline asm: compiler cannot re-materialize ---
    uint4 W0, W1, W2, W3, W4, W5, W6, W7, W8, W9, W10, W11, W12, W13, W14, W15;
    {
        const u32* wp = g_Wi8 + (size_t)t * 64;
        asm volatile(
            "global_load_dwordx4 %0, %16, off\n\t"
            "global_load_dwordx4 %1, %16, off offset:16\n\t"
            "global_load_dwordx4 %2, %16, off offset:32\n\t"
            "global_load_dwordx4 %3, %16, off offset:48\n\t"
            "global_load_dwordx4 %4, %16, off offset:64\n\t"
            "global_load_dwordx4 %5, %16, off offset:80\n\t"
            "global_load_dwordx4 %6, %16, off offset:96\n\t"
            "global_load_dwordx4 %7, %16, off offset:112\n\t"
            "global_load_dwordx4 %8, %16, off offset:128\n\t"
            "global_load_dwordx4 %9, %16, off offset:144\n\t"
            "global_load_dwordx4 %10, %16, off offset:160\n\t"
            "global_load_dwordx4 %11, %16, off offset:176\n\t"
            "global_load_dwordx4 %12, %16, off offset:192\n\t"
            "global_load_dwordx4 %13, %16, off offset:208\n\t"
            "global_load_dwordx4 %14, %16, off offset:224\n\t"
            "global_load_dwordx4 %15, %16, off offset:240\n\t"
            "s_waitcnt vmcnt(0)"
            : "=&v"(W0), "=&v"(W1), "=&v"(W2), "=&v"(W3),
              "=&v"(W4), "=&v"(W5), "=&v"(W6), "=&v"(W7),
              "=&v"(W8), "=&v"(W9), "=&v"(W10), "=&v"(W11),
              "=&v"(W12), "=&v"(W13), "=&v"(W14), "=&v"(W15)
            : "v"(wp));
    }
    const float wsc = g_wscale[t];
    const int is_tanh_col = ((t & 3) == 2);

    // --- init state ---
    float c_reg = 0.0f, wo = 0.0f;
    if (t < H_) {
        c_reg = ldin(mode, c0, (size_t)b * H_ + t);
        wo = ldin(mode, Wout, t);
    }
    if (t < H_ / 4) {
        u32 pk = 0;
#pragma unroll
        for (int i = 0; i < 4; ++i) {
            float h = ldin(mode, h0, (size_t)b * H_ + 4 * t + i);
            int q = (int)rintf(fminf(fmaxf(h, -1.0f), 1.0f) * 127.0f);
            pk |= ((u32)(q & 0xff)) << (8 * i);
        }
        h8[t] = pk;
    }
    const float bo = ldin(mode, bout, 0);
    const u16* xp = g_xg + (size_t)b * S_ * G_ + t;
    u16 xv = xp[0];
    __syncthreads();

    for (int s = 0; s < S_; ++s) {
        // dot over K=256: 16 broadcast uint4 LDS reads + 64 int8 dot4s
        int acc = 0;
        const uint4* hp = (const uint4*)h8;
#define DOT16(WV, IDX)                                   \
        {                                                \
            uint4 hv = hp[IDX];                          \
            acc = dot4i8(hv.x, WV.x, acc);               \
            acc = dot4i8(hv.y, WV.y, acc);               \
            acc = dot4i8(hv.z, WV.z, acc);               \
            acc = dot4i8(hv.w, WV.w, acc);               \
        }
        DOT16(W0, 0)  DOT16(W1, 1)  DOT16(W2, 2)  DOT16(W3, 3)
        DOT16(W4, 4)  DOT16(W5, 5)  DOT16(W6, 6)  DOT16(W7, 7)
        DOT16(W8, 8)  DOT16(W9, 9)  DOT16(W10, 10) DOT16(W11, 11)
        DOT16(W12, 12) DOT16(W13, 13) DOT16(W14, 14) DOT16(W15, 15)
#undef DOT16
        // activation computed per-thread by ALL 1024 threads (spreads transcendentals)
        float pre = clamp30((float)acc * wsc + b2f(xv));
        gl[t] = is_tanh_col ? tanhf_(pre) : sigmoidf_(pre);
        if (s + 1 < S_) xv = xp[(size_t)(s + 1) * G_];   // prefetch next step's xg
        __syncthreads();                          // (1) activations ready; h8 reads done

        if (t < H_) {
            float4 a4 = *(const float4*)(gl + 4 * t);    // ii, ff, gv, oo
            c_reg = fmaf(a4.y, c_reg, a4.x * a4.z);
            float h = a4.w * tanhf_(c_reg);
            // quantize + pack 4 lanes' h into one u32 (unit t -> byte t&3 of word t>>2)
            int q = (int)rintf(fminf(fmaxf(h, -1.0f), 1.0f) * 127.0f) & 0xff;
            int q1 = __shfl_down(q, 1, 64);
            int q2 = __shfl_down(q, 2, 64);
            int q3 = __shfl_down(q, 3, 64);
            if ((t & 3) == 0)
                h8[t >> 2] = (u32)q | ((u32)q1 << 8) | ((u32)q2 << 16) | ((u32)q3 << 24);
            // output head partial
            float p = h * wo;
#pragma unroll
            for (int off = 32; off > 0; off >>= 1) p += __shfl_down(p, off, 64);
            if ((t & 63) == 0) red[t >> 6] = p;
        }
        __syncthreads();                          // (2) h8 + red ready

        if (t == 0) {
            float yf = sigmoidf_(clamp30(red[0] + red[1] + red[2] + red[3] + bo));
            if (mode) ((float*)yv)[(size_t)s * B_ + b] = yf;
            else      ((u16*)yv)[(size_t)s * B_ + b] = f2b(yf);
        }
    }
}

extern "C" void kernel_launch(void* const* d_in, const int* in_sizes, int n_in,
                              void* d_out, int out_size, void* d_ws, size_t ws_size,
                              hipStream_t stream) {
    const void* pw   = d_in[0];   // [B,S,50]
    const void* Wemb = d_in[1];   // [E,50]
    const void* bemb = d_in[2];   // [E]
    const void* Wih  = d_in[3];   // [G,E]
    const void* Whh  = d_in[4];   // [G,H]
    const void* bih  = d_in[5];   // [G]
    const void* bhh  = d_in[6];   // [G]
    const void* Wout = d_in[7];   // [1,H]
    const void* bout = d_in[8];   // [1]
    const void* h0   = d_in[9];   // [B,H]
    const void* c0   = d_in[10];  // [B,H]
    void* y = d_out;              // [S,B]
    (void)d_ws; (void)ws_size;

    sniff_kernel<<<1, 1, 0, stream>>>((const u16*)Wemb);
    transpose_wih<<<(E_ * G_) / 256, 256, 0, stream>>>(Wih);
    prep_wi8<<<G_ / 256, 256, 0, stream>>>(Whh);
    xg_kernel<<<(B_ * S_) / 16, 256, 0, stream>>>(pw, Wemb, bemb, bih, bhh);
    lstm_i8<<<B_, 1024, 0, stream>>>(Wout, bout, h0, c0, y);
}

// Round 10
// 3317.372 us; speedup vs baseline: 1.0629x; 1.0629x over previous
//
#include <hip/hip_runtime.h>
#include <hip/hip_bf16.h>

// B=64, S=2048, WIN=50, E=128, H=256, G=4H=1024.
#define B_ 64
#define S_ 2048
#define W_ 50
#define E_ 128
#define H_ 256
#define G_ 1024

typedef unsigned short u16;
typedef unsigned int u32;
typedef unsigned int v4u __attribute__((ext_vector_type(4)));   // true vector type for asm "v"

// Module-global scratch (BSS; d_ws untrusted).
__device__ int g_mode;                          // 0 = bf16 buffers, 1 = fp32 buffers
__device__ u16 g_WihT[E_ * G_];                 // [e][4u+q] = Wih[q*H+u][e]  (bf16)
__device__ u32 g_Wi8[G_ * 64];                  // [c][j]: 4×i8 = Whh[row(c)][4j..4j+3], row(c)=(c&3)*256+(c>>2)
__device__ float g_wscale[G_];                  // per-column dequant: max|W[:,c]| /(127*127)
__device__ u16 g_xg[(size_t)B_ * S_ * G_];      // [b][s][1024] bf16, biases folded (validated)

__device__ __forceinline__ float b2f(u16 u) {
    union { u32 i; float f; } v;
    v.i = ((u32)u) << 16;
    return v.f;
}
__device__ __forceinline__ u16 f2b(float f) {
    __hip_bfloat16 h = __float2bfloat16(f);
    return *reinterpret_cast<u16*>(&h);
}
__device__ __forceinline__ float ldin(int mode, const void* p, size_t i) {
    return mode ? ((const float*)p)[i] : b2f(((const u16*)p)[i]);
}
__device__ __forceinline__ float clamp30(float x) {
    return fminf(fmaxf(x, -30.0f), 30.0f);
}
__device__ __forceinline__ float sigmoidf_(float x) { return 1.0f / (1.0f + __expf(-x)); }
__device__ __forceinline__ float tanhf_(float x) {
    float e = __expf(2.0f * x);
    return 1.0f - 2.0f / (e + 1.0f);
}
// int8x4 dot: acc += sum_i (i8)a[i] * (i8)b[i]
__device__ __forceinline__ int dot4i8(u32 a, u32 b, int acc) {
#if __has_builtin(__builtin_amdgcn_sdot4)
    return __builtin_amdgcn_sdot4(a, b, acc, false);
#else
    acc += (int)(signed char)(a)       * (int)(signed char)(b);
    acc += (int)(signed char)(a >> 8)  * (int)(signed char)(b >> 8);
    acc += (int)(signed char)(a >> 16) * (int)(signed char)(b >> 16);
    acc += (int)(signed char)(a >> 24) * (int)(signed char)(b >> 24);
    return acc;
#endif
}

// ---------- K0: dtype sniffer (validated) ----------
__global__ void sniff_kernel(const u16* __restrict__ wemb) {
    int sane = 0;
    for (int i = 0; i < 2048; ++i) {
        int ex = (wemb[i] >> 7) & 0xFF;
        if (ex == 0 || (ex >= 96 && ex <= 143)) ++sane;
    }
    g_mode = (sane >= 1900) ? 0 : 1;
}

// ---------- K0b: Wih gate-interleaved transpose (for xg_kernel) ----------
__global__ __launch_bounds__(256) void transpose_wih(const void* __restrict__ src) {
    const int mode = g_mode;
    int i = blockIdx.x * 256 + threadIdx.x;          // i = e*G + 4u+q
    int e = i >> 10, r = i & 1023, u = r >> 2, q = r & 3;
    g_WihT[i] = f2b(ldin(mode, src, (size_t)((q << 15) + (u << 7) + e)));
}

// ---------- K0c: Whh -> int8 per-column-scaled, [c][j] layout (validated) ----------
__global__ __launch_bounds__(256) void prep_wi8(const void* __restrict__ src) {
    const int mode = g_mode;
    int c = blockIdx.x * 256 + threadIdx.x;          // 0..1023
    int row = ((c & 3) << 8) + (c >> 2);
    const size_t base = (size_t)row * H_;
    float m = 0.0f;
    for (int k = 0; k < H_; ++k) m = fmaxf(m, fabsf(ldin(mode, src, base + k)));
    float inv = (m > 0.0f) ? 127.0f / m : 0.0f;
    g_wscale[c] = m / (127.0f * 127.0f);             // w-scale * h-scale(1/127)
    for (int j = 0; j < 64; ++j) {
        u32 pk = 0;
#pragma unroll
        for (int i = 0; i < 4; ++i) {
            int q = (int)rintf(ldin(mode, src, base + 4 * j + i) * inv);
            q = max(-127, min(127, q));
            pk |= ((u32)(q & 0xff)) << (8 * i);
        }
        g_Wi8[(size_t)c * 64 + j] = pk;              // contiguous per column
    }
}

// ---------- K1: fused embedding + input projection (validated round 4) ----------
__global__ __launch_bounds__(256) void xg_kernel(const void* __restrict__ pw,
                                                 const void* __restrict__ Wemb,
                                                 const void* __restrict__ bemb,
                                                 const void* __restrict__ bih,
                                                 const void* __restrict__ bhh) {
    const int mode = g_mode;
    const int t = threadIdx.x;
    const int m0 = blockIdx.x * 16;
    __shared__ float pw16[16][W_ + 2];
    __shared__ float Wl[E_ * 51];
    __shared__ __align__(16) float erow[16][E_];

    for (int i = t; i < E_ * W_; i += 256) {
        int e = i / W_, w = i - e * W_;
        Wl[e * 51 + w] = ldin(mode, Wemb, i);
    }
    for (int i = t; i < 16 * W_; i += 256) {
        int r = i / W_, w = i - r * W_;
        pw16[r][w] = ldin(mode, pw, (size_t)(m0 + r) * W_ + w);
    }
    __syncthreads();

#pragma unroll
    for (int i = 0; i < 8; ++i) {
        int idx = i * 256 + t;
        int r = idx >> 7, e = idx & 127;
        float a = ldin(mode, bemb, e);
        const float* wr = &Wl[e * 51];
#pragma unroll
        for (int w = 0; w < W_; ++w) a = fmaf(pw16[r][w], wr[w], a);
        erow[r][e] = fmaxf(a, 0.0f);
    }
    __syncthreads();

    const int g0 = 4 * t;
    float acc[16][4];
    {
        float b0 = ldin(mode, bih, t) + ldin(mode, bhh, t);
        float b1 = ldin(mode, bih, H_ + t) + ldin(mode, bhh, H_ + t);
        float b2 = ldin(mode, bih, 2 * H_ + t) + ldin(mode, bhh, 2 * H_ + t);
        float b3 = ldin(mode, bih, 3 * H_ + t) + ldin(mode, bhh, 3 * H_ + t);
#pragma unroll
        for (int r = 0; r < 16; ++r) { acc[r][0] = b0; acc[r][1] = b1; acc[r][2] = b2; acc[r][3] = b3; }
    }
    for (int e = 0; e < E_; e += 4) {
        ushort4 w0 = *(const ushort4*)(g_WihT + (size_t)(e + 0) * G_ + g0);
        ushort4 w1 = *(const ushort4*)(g_WihT + (size_t)(e + 1) * G_ + g0);
        ushort4 w2 = *(const ushort4*)(g_WihT + (size_t)(e + 2) * G_ + g0);
        ushort4 w3 = *(const ushort4*)(g_WihT + (size_t)(e + 3) * G_ + g0);
        float f00 = b2f(w0.x), f01 = b2f(w0.y), f02 = b2f(w0.z), f03 = b2f(w0.w);
        float f10 = b2f(w1.x), f11 = b2f(w1.y), f12 = b2f(w1.z), f13 = b2f(w1.w);
        float f20 = b2f(w2.x), f21 = b2f(w2.y), f22 = b2f(w2.z), f23 = b2f(w2.w);
        float f30 = b2f(w3.x), f31 = b2f(w3.y), f32 = b2f(w3.z), f33 = b2f(w3.w);
#pragma unroll
        for (int r = 0; r < 16; ++r) {
            float4 ev = *(const float4*)&erow[r][e];
            acc[r][0] = fmaf(ev.x, f00, acc[r][0]); acc[r][1] = fmaf(ev.x, f01, acc[r][1]);
            acc[r][2] = fmaf(ev.x, f02, acc[r][2]); acc[r][3] = fmaf(ev.x, f03, acc[r][3]);
            acc[r][0] = fmaf(ev.y, f10, acc[r][0]); acc[r][1] = fmaf(ev.y, f11, acc[r][1]);
            acc[r][2] = fmaf(ev.y, f12, acc[r][2]); acc[r][3] = fmaf(ev.y, f13, acc[r][3]);
            acc[r][0] = fmaf(ev.z, f20, acc[r][0]); acc[r][1] = fmaf(ev.z, f21, acc[r][1]);
            acc[r][2] = fmaf(ev.z, f22, acc[r][2]); acc[r][3] = fmaf(ev.z, f23, acc[r][3]);
            acc[r][0] = fmaf(ev.w, f30, acc[r][0]); acc[r][1] = fmaf(ev.w, f31, acc[r][1]);
            acc[r][2] = fmaf(ev.w, f32, acc[r][2]); acc[r][3] = fmaf(ev.w, f33, acc[r][3]);
        }
    }
#pragma unroll
    for (int r = 0; r < 16; ++r) {
        ushort4 sv;
        sv.x = f2b(acc[r][0]); sv.y = f2b(acc[r][1]);
        sv.z = f2b(acc[r][2]); sv.w = f2b(acc[r][3]);
        *(ushort4*)(g_xg + (size_t)(m0 + r) * G_ + g0) = sv;
    }
}

// ---------- K2: recurrence; W_hh pinned in VGPRs (ext-vector asm + pinned occupancy) ----------
// 64 blocks x 1024 threads; thread t owns gate-column t (4*unit+gate), all K=256 as
// 16 v4u loaded once by asm volatile. amdgpu_waves_per_eu(4,4) pins the backend's
// occupancy target to 4 waves/EU (1 block/CU) -> 128-VGPR budget, no spill incentive.
__global__ __launch_bounds__(1024)
__attribute__((amdgpu_waves_per_eu(4, 4)))
void lstm_i8(const void* __restrict__ Wout,
             const void* __restrict__ bout,
             const void* __restrict__ h0,
             const void* __restrict__ c0,
             void* __restrict__ yv) {
    const int mode = g_mode;
    const int t = threadIdx.x;
    const int b = blockIdx.x;

    __shared__ __align__(16) u32 h8[H_ / 4];     // h as i8, 64 words
    __shared__ __align__(16) float gl[G_];       // gate pre-activations
    __shared__ float red[4];

    // --- weights into 16 v4u via inline asm (vector-typed operands -> VReg_128) ---
    v4u W0, W1, W2, W3, W4, W5, W6, W7, W8, W9, W10, W11, W12, W13, W14, W15;
    {
        const u32* wp = g_Wi8 + (size_t)t * 64;
        asm volatile(
            "global_load_dwordx4 %0, %16, off\n\t"
            "global_load_dwordx4 %1, %16, off offset:16\n\t"
            "global_load_dwordx4 %2, %16, off offset:32\n\t"
            "global_load_dwordx4 %3, %16, off offset:48\n\t"
            "global_load_dwordx4 %4, %16, off offset:64\n\t"
            "global_load_dwordx4 %5, %16, off offset:80\n\t"
            "global_load_dwordx4 %6, %16, off offset:96\n\t"
            "global_load_dwordx4 %7, %16, off offset:112\n\t"
            "global_load_dwordx4 %8, %16, off offset:128\n\t"
            "global_load_dwordx4 %9, %16, off offset:144\n\t"
            "global_load_dwordx4 %10, %16, off offset:160\n\t"
            "global_load_dwordx4 %11, %16, off offset:176\n\t"
            "global_load_dwordx4 %12, %16, off offset:192\n\t"
            "global_load_dwordx4 %13, %16, off offset:208\n\t"
            "global_load_dwordx4 %14, %16, off offset:224\n\t"
            "global_load_dwordx4 %15, %16, off offset:240\n\t"
            "s_waitcnt vmcnt(0)"
            : "=&v"(W0), "=&v"(W1), "=&v"(W2), "=&v"(W3),
              "=&v"(W4), "=&v"(W5), "=&v"(W6), "=&v"(W7),
              "=&v"(W8), "=&v"(W9), "=&v"(W10), "=&v"(W11),
              "=&v"(W12), "=&v"(W13), "=&v"(W14), "=&v"(W15)
            : "v"(wp));
    }
    const float wsc = g_wscale[t];

    // --- init state ---
    float c_reg = 0.0f, wo = 0.0f;
    if (t < H_) {
        c_reg = ldin(mode, c0, (size_t)b * H_ + t);
        wo = ldin(mode, Wout, t);
    }
    if (t < H_ / 4) {
        u32 pk = 0;
#pragma unroll
        for (int i = 0; i < 4; ++i) {
            float h = ldin(mode, h0, (size_t)b * H_ + 4 * t + i);
            int q = (int)rintf(fminf(fmaxf(h, -1.0f), 1.0f) * 127.0f);
            pk |= ((u32)(q & 0xff)) << (8 * i);
        }
        h8[t] = pk;
    }
    const float bo = ldin(mode, bout, 0);
    const u16* xp = g_xg + (size_t)b * S_ * G_ + t;
    u16 xv = xp[0];
    __syncthreads();

    for (int s = 0; s < S_; ++s) {
        // dot over K=256: 16 broadcast uint4 LDS reads + 64 int8 dot4s
        int acc = 0;
        const uint4* hp = (const uint4*)h8;
#define DOT16(WV, IDX)                                   \
        {                                                \
            uint4 hv = hp[IDX];                          \
            acc = dot4i8(hv.x, WV.x, acc);               \
            acc = dot4i8(hv.y, WV.y, acc);               \
            acc = dot4i8(hv.z, WV.z, acc);               \
            acc = dot4i8(hv.w, WV.w, acc);               \
        }
        DOT16(W0, 0)  DOT16(W1, 1)  DOT16(W2, 2)  DOT16(W3, 3)
        DOT16(W4, 4)  DOT16(W5, 5)  DOT16(W6, 6)  DOT16(W7, 7)
        DOT16(W8, 8)  DOT16(W9, 9)  DOT16(W10, 10) DOT16(W11, 11)
        DOT16(W12, 12) DOT16(W13, 13) DOT16(W14, 14) DOT16(W15, 15)
#undef DOT16
        gl[t] = (float)acc * wsc + b2f(xv);
        if (s + 1 < S_) xv = xp[(size_t)(s + 1) * G_];   // prefetch next step's xg
        __syncthreads();                          // (1) gates ready; h8 reads done

        if (t < H_) {
            float4 g4 = *(const float4*)(gl + 4 * t);
            float ii = sigmoidf_(clamp30(g4.x));
            float ff = sigmoidf_(clamp30(g4.y));
            float gv = tanhf_(clamp30(g4.z));
            float oo = sigmoidf_(clamp30(g4.w));
            c_reg = fmaf(ff, c_reg, ii * gv);
            float h = oo * tanhf_(c_reg);
            // quantize + pack 4 lanes' h into one u32 (unit t -> byte t&3 of word t>>2)
            int q = (int)rintf(fminf(fmaxf(h, -1.0f), 1.0f) * 127.0f) & 0xff;
            int q1 = __shfl_down(q, 1, 64);
            int q2 = __shfl_down(q, 2, 64);
            int q3 = __shfl_down(q, 3, 64);
            if ((t & 3) == 0)
                h8[t >> 2] = (u32)q | ((u32)q1 << 8) | ((u32)q2 << 16) | ((u32)q3 << 24);
            // output head partial
            float p = h * wo;
#pragma unroll
            for (int off = 32; off > 0; off >>= 1) p += __shfl_down(p, off, 64);
            if ((t & 63) == 0) red[t >> 6] = p;
        }
        __syncthreads();                          // (2) h8 + red ready

        if (t == 0) {
            float yf = sigmoidf_(clamp30(red[0] + red[1] + red[2] + red[3] + bo));
            if (mode) ((float*)yv)[(size_t)s * B_ + b] = yf;
            else      ((u16*)yv)[(size_t)s * B_ + b] = f2b(yf);
        }
    }
}

extern "C" void kernel_launch(void* const* d_in, const int* in_sizes, int n_in,
                              void* d_out, int out_size, void* d_ws, size_t ws_size,
                              hipStream_t stream) {
    const void* pw   = d_in[0];   // [B,S,50]
    const void* Wemb = d_in[1];   // [E,50]
    const void* bemb = d_in[2];   // [E]
    const void* Wih  = d_in[3];   // [G,E]
    const void* Whh  = d_in[4];   // [G,H]
    const void* bih  = d_in[5];   // [G]
    const void* bhh  = d_in[6];   // [G]
    const void* Wout = d_in[7];   // [1,H]
    const void* bout = d_in[8];   // [1]
    const void* h0   = d_in[9];   // [B,H]
    const void* c0   = d_in[10];  // [B,H]
    void* y = d_out;              // [S,B]
    (void)d_ws; (void)ws_size;

    sniff_kernel<<<1, 1, 0, stream>>>((const u16*)Wemb);
    transpose_wih<<<(E_ * G_) / 256, 256, 0, stream>>>(Wih);
    prep_wi8<<<G_ / 256, 256, 0, stream>>>(Whh);
    xg_kernel<<<(B_ * S_) / 16, 256, 0, stream>>>(pw, Wemb, bemb, bih, bhh);
    lstm_i8<<<B_, 1024, 0, stream>>>(Wout, bout, h0, c0, y);
}